// Round 9
// baseline (501.580 us; speedup 1.0000x reference)
//
#include <hip/hip_runtime.h>

#define NS 131072
#define KC 8
typedef unsigned long long u64;

#define LD4(P) (*reinterpret_cast<const float4*>(&sm[(P)]))
#define LD2(P) (*reinterpret_cast<const float2*>(&sm[(P)]))
#define ST4(P) (*reinterpret_cast<float4*>(&sm[(P)]))
#define ST2(P) (*reinterpret_cast<float2*>(&sm[(P)]))
#define GL4(P) (*reinterpret_cast<const float4*>(&(P)))

#define FMA8(ACCR, AV, W0, W1) do { \
  ACCR[0]=fmaf((AV),(W0).x,ACCR[0]); ACCR[1]=fmaf((AV),(W0).y,ACCR[1]); \
  ACCR[2]=fmaf((AV),(W0).z,ACCR[2]); ACCR[3]=fmaf((AV),(W0).w,ACCR[3]); \
  ACCR[4]=fmaf((AV),(W1).x,ACCR[4]); ACCR[5]=fmaf((AV),(W1).y,ACCR[5]); \
  ACCR[6]=fmaf((AV),(W1).z,ACCR[6]); ACCR[7]=fmaf((AV),(W1).w,ACCR[7]); } while(0)

// 4-wide K step: A rows st+32m (col AK*4), B rows BK*4.. (cols JOFF..JOFF+7).
// 16 LDS b128 reads per 256 FMAs. All register indices compile-time static.
#define K4(ACC, ABASE, ASTR, AK, BBASE, BSTR, JOFF, BK) do { \
  const float4 b00=LD4((BBASE)+((BK)*4+0)*(BSTR)+(JOFF)), b01=LD4((BBASE)+((BK)*4+0)*(BSTR)+(JOFF)+4); \
  const float4 b10=LD4((BBASE)+((BK)*4+1)*(BSTR)+(JOFF)), b11=LD4((BBASE)+((BK)*4+1)*(BSTR)+(JOFF)+4); \
  const float4 b20=LD4((BBASE)+((BK)*4+2)*(BSTR)+(JOFF)), b21=LD4((BBASE)+((BK)*4+2)*(BSTR)+(JOFF)+4); \
  const float4 b30=LD4((BBASE)+((BK)*4+3)*(BSTR)+(JOFF)), b31=LD4((BBASE)+((BK)*4+3)*(BSTR)+(JOFF)+4); \
  _Pragma("unroll") \
  for (int m_ = 0; m_ < 8; ++m_) { \
    const float4 av = LD4((ABASE)+(st+32*m_)*(ASTR)+(AK)*4); \
    FMA8(ACC[m_], av.x, b00, b01); FMA8(ACC[m_], av.y, b10, b11); \
    FMA8(ACC[m_], av.z, b20, b21); FMA8(ACC[m_], av.w, b30, b31); } \
} while(0)

#define INIT88(ACC, BPTR, OFF) do { \
  const float4 u_ = *reinterpret_cast<const float4*>(&(BPTR)[(OFF)]); \
  const float4 v_ = *reinterpret_cast<const float4*>(&(BPTR)[(OFF)+4]); \
  _Pragma("unroll") for (int m_ = 0; m_ < 8; ++m_) { \
    ACC[m_][0]=u_.x; ACC[m_][1]=u_.y; ACC[m_][2]=u_.z; ACC[m_][3]=u_.w; \
    ACC[m_][4]=v_.x; ACC[m_][5]=v_.y; ACC[m_][6]=v_.z; ACC[m_][7]=v_.w; } \
} while(0)

#define RELU88(ACC) do { _Pragma("unroll") for (int m_=0;m_<8;++m_) \
  { _Pragma("unroll") for (int j_=0;j_<8;++j_) ACC[m_][j_]=fmaxf(ACC[m_][j_],0.f); } } while(0)

// write 8x8 reg tile into arena rows (stride 68), cols job..job+7
#define WRITE_E(ACC) do { _Pragma("unroll") for (int m_=0;m_<8;++m_){ \
  const int r_ = st + 32*m_; \
  ST4(AR + r_*68 + job)     = make_float4(ACC[m_][0],ACC[m_][1],ACC[m_][2],ACC[m_][3]); \
  ST4(AR + r_*68 + job + 4) = make_float4(ACC[m_][4],ACC[m_][5],ACC[m_][6],ACC[m_][7]); } } while(0)

// write staged registers into AR [256][20] staging layout
#define STAGE_X() do { \
  ST4(AR + (xr0      )*20 + xc) = rx0; \
  ST4(AR + (xr0 +  64)*20 + xc) = rx1; \
  ST4(AR + (xr0 + 128)*20 + xc) = rx2; \
  ST4(AR + (xr0 + 192)*20 + xc) = rx3; } while(0)

// ---------------------------------------------------------------------------
// k_enc arena layout (words):
// AR  [0,17408)      : staging [256][20] -> e1/e2 [256][68] -> z/d [256][20]
// WB  [17408,18496)  : W1/W2 chunks [16][68] -> W3 [64][16] -> Wd2 halves
// WD1 [18496,18752)  : Wd1 [16][16]
// total 18752 words = 75008 B -> 2 blocks/CU
// stride 68: A-read banks 4r%32 -> conflict-free; stride 20: 4r%32 likewise.
// ---------------------------------------------------------------------------
#define AR  0
#define WB  17408
#define WD1 18496
#define SMW 18752

__global__ __launch_bounds__(256, 1) void k_enc(
    const float* __restrict__ x,
    const float* __restrict__ We1, const float* __restrict__ be1,
    const float* __restrict__ We2, const float* __restrict__ be2,
    const float* __restrict__ We3, const float* __restrict__ be3,
    const float* __restrict__ Wd1, const float* __restrict__ bd1,
    const float* __restrict__ Wd2, const float* __restrict__ bd2,
    const float* __restrict__ centers,
    float* __restrict__ out_z, float* __restrict__ out_q,
    float* __restrict__ xhat, float* __restrict__ rec, float* __restrict__ kld,
    int* __restrict__ cidx, int* __restrict__ counts)
{
    __shared__ float sm[SMW];
    const int t  = threadIdx.x;
    const int ot = t & 7, st = t >> 3;
    const int job = ot * 8;
    const int s0 = blockIdx.x * 256;
    const int xr0 = t >> 2, xc = (t & 3) * 4;      // x-staging mapping
    const int wr  = t >> 4, wc = (t & 15) * 4;     // weight-staging mapping

    // ================= L1: K=128, 8 chunks of 16, T14 prefetch =================
    {
        float acc1[8][8];
        INIT88(acc1, be1, job);
        float4 rx0 = GL4(x[(size_t)(s0+xr0      )*128 + xc]);
        float4 rx1 = GL4(x[(size_t)(s0+xr0 +  64)*128 + xc]);
        float4 rx2 = GL4(x[(size_t)(s0+xr0 + 128)*128 + xc]);
        float4 rx3 = GL4(x[(size_t)(s0+xr0 + 192)*128 + xc]);
        float4 rw  = GL4(We1[(size_t)wr*64 + wc]);
        #pragma unroll 1
        for (int c = 0; c < 8; ++c) {
            __syncthreads();                      // prev chunk reads done
            STAGE_X();
            ST4(WB + wr*68 + wc) = rw;
            __syncthreads();                      // staging visible
            if (c < 7) {                          // issue next-chunk loads now
                rx0 = GL4(x[(size_t)(s0+xr0      )*128 + (c+1)*16 + xc]);
                rx1 = GL4(x[(size_t)(s0+xr0 +  64)*128 + (c+1)*16 + xc]);
                rx2 = GL4(x[(size_t)(s0+xr0 + 128)*128 + (c+1)*16 + xc]);
                rx3 = GL4(x[(size_t)(s0+xr0 + 192)*128 + (c+1)*16 + xc]);
                rw  = GL4(We1[(size_t)((c+1)*16 + wr)*64 + wc]);
            }
            #pragma unroll
            for (int kc = 0; kc < 4; ++kc) K4(acc1, AR, 20, kc, WB, 68, job, kc);
        }
        __syncthreads();                          // all staging reads done
        RELU88(acc1);
        WRITE_E(acc1);                            // e1 -> arena stride 68
    }

    // ================= L2: K=64, 4 weight chunks, T14 prefetch =================
    {
        float acc2[8][8];
        INIT88(acc2, be2, job);
        float4 rw = GL4(We2[(size_t)wr*64 + wc]);
        #pragma unroll 1
        for (int c = 0; c < 4; ++c) {
            __syncthreads();                      // WB free / e1 visible
            ST4(WB + wr*68 + wc) = rw;
            __syncthreads();
            if (c < 3) rw = GL4(We2[(size_t)((c+1)*16 + wr)*64 + wc]);
            #pragma unroll
            for (int kc = 0; kc < 4; ++kc) K4(acc2, AR, 68, c*4 + kc, WB, 68, job, kc);
        }
        __syncthreads();                          // e1/WB reads done
        RELU88(acc2);
        WRITE_E(acc2);                            // e2 overwrites e1
    }
    // stage W3 [64][16] -> WB ; Wd1 -> WD1
    {   const int row = t >> 2, c4 = (t & 3) * 4;
        ST4(WB + row*16 + c4) = GL4(We3[(size_t)row*16 + c4]); }
    if (t < 64) ST4(WD1 + (t >> 2)*16 + (t & 3)*4) =
        GL4(Wd1[(t >> 2)*16 + (t & 3)*4]);
    __syncthreads();

    // ================= L3: z, K=64, N=2/thread =================
    float zac[8][2];
    {   const float2 b3 = *reinterpret_cast<const float2*>(&be3[ot*2]);
        #pragma unroll
        for (int m = 0; m < 8; ++m) { zac[m][0] = b3.x; zac[m][1] = b3.y; } }
    #pragma unroll 2
    for (int kc = 0; kc < 16; ++kc) {
        const float2 w0 = LD2(WB + (kc*4+0)*16 + ot*2);
        const float2 w1 = LD2(WB + (kc*4+1)*16 + ot*2);
        const float2 w2 = LD2(WB + (kc*4+2)*16 + ot*2);
        const float2 w3 = LD2(WB + (kc*4+3)*16 + ot*2);
        #pragma unroll
        for (int m = 0; m < 8; ++m) {
            const float4 av = LD4(AR + (st + 32*m)*68 + kc*4);
            float sa = zac[m][0], sb = zac[m][1];
            sa = fmaf(av.x, w0.x, sa); sb = fmaf(av.x, w0.y, sb);
            sa = fmaf(av.y, w1.x, sa); sb = fmaf(av.y, w1.y, sb);
            sa = fmaf(av.z, w2.x, sa); sb = fmaf(av.z, w2.y, sb);
            sa = fmaf(av.w, w3.x, sa); sb = fmaf(av.w, w3.y, sb);
            zac[m][0] = sa; zac[m][1] = sb;
        }
    }
    #pragma unroll
    for (int m = 0; m < 8; ++m)
        *reinterpret_cast<float2*>(&out_z[(size_t)(s0 + st + 32*m)*16 + ot*2]) =
            make_float2(zac[m][0], zac[m][1]);
    __syncthreads();              // all e2 + W3 reads done
    #pragma unroll
    for (int m = 0; m < 8; ++m)
        ST2(AR + (st + 32*m)*20 + ot*2) = make_float2(zac[m][0], zac[m][1]);
    {   // stage Wd2 half0 [16][0..63] -> WB
        ST4(WB + wr*68 + wc) = GL4(Wd2[(size_t)wr*128 + wc]); }
    __syncthreads();

    // ======== per-thread row t: student-t + softmax + argmax + counts ========
    // Direct d2 = sum((z-c)^2) in fp32 — exactly matches reference argmax.
    {
        const float4 z0 = LD4(AR + t*20 + 0), z1 = LD4(AR + t*20 + 4);
        const float4 z2 = LD4(AR + t*20 + 8), z3 = LD4(AR + t*20 + 12);
        const float zz[16] = {z0.x,z0.y,z0.z,z0.w, z1.x,z1.y,z1.z,z1.w,
                              z2.x,z2.y,z2.z,z2.w, z3.x,z3.y,z3.z,z3.w};
        float d2[KC];
        #pragma unroll
        for (int k = 0; k < KC; ++k) {
            float acc = 0.f;
            #pragma unroll
            for (int l = 0; l < 16; ++l) {
                const float dl = zz[l] - centers[k*16 + l];
                acc = fmaf(dl, dl, acc);
            }
            d2[k] = acc;
        }
        float lgt[KC], ex[KC];
        float mm = -1e30f;
        #pragma unroll
        for (int k = 0; k < KC; ++k) { lgt[k] = -log1pf(d2[k]); mm = fmaxf(mm, lgt[k]); }
        float ssum = 0.f;
        #pragma unroll
        for (int k = 0; k < KC; ++k) { ex[k] = expf(lgt[k] - mm); ssum += ex[k]; }
        const float inv = 1.f / ssum;
        float4* oq = reinterpret_cast<float4*>(&out_q[(size_t)(s0 + t)*8]);
        oq[0] = make_float4(ex[0]*inv, ex[1]*inv, ex[2]*inv, ex[3]*inv);
        oq[1] = make_float4(ex[4]*inv, ex[5]*inv, ex[6]*inv, ex[7]*inv);
        int ci = 0; float best = d2[0];
        #pragma unroll
        for (int k = 1; k < KC; ++k) if (d2[k] < best) { best = d2[k]; ci = k; }
        cidx[s0 + t] = ci;
        #pragma unroll
        for (int k = 0; k < KC; ++k) {
            const u64 mk = __ballot(ci == k);
            if ((t & 63) == 0 && mk) atomicAdd(&counts[k], (int)__popcll(mk));
        }
        kld[s0 + t] = 0.f;
    }

    // ================= decoder: d = relu(z Wd1 + bd1), N=2/thread =================
    {
        float dac[8][2];
        const float2 bb = *reinterpret_cast<const float2*>(&bd1[ot*2]);
        const float2 u0 = LD2(WD1 + 0*16 + ot*2),  u1 = LD2(WD1 + 1*16 + ot*2);
        const float2 u2 = LD2(WD1 + 2*16 + ot*2),  u3 = LD2(WD1 + 3*16 + ot*2);
        const float2 u4 = LD2(WD1 + 4*16 + ot*2),  u5 = LD2(WD1 + 5*16 + ot*2);
        const float2 u6 = LD2(WD1 + 6*16 + ot*2),  u7 = LD2(WD1 + 7*16 + ot*2);
        const float2 u8 = LD2(WD1 + 8*16 + ot*2),  u9 = LD2(WD1 + 9*16 + ot*2);
        const float2 uA = LD2(WD1 + 10*16 + ot*2), uB = LD2(WD1 + 11*16 + ot*2);
        const float2 uC = LD2(WD1 + 12*16 + ot*2), uD = LD2(WD1 + 13*16 + ot*2);
        const float2 uE = LD2(WD1 + 14*16 + ot*2), uF = LD2(WD1 + 15*16 + ot*2);
        #pragma unroll
        for (int m = 0; m < 8; ++m) {
            const int r = st + 32*m;
            const float4 a0 = LD4(AR + r*20 + 0), a1 = LD4(AR + r*20 + 4);
            const float4 a2 = LD4(AR + r*20 + 8), a3 = LD4(AR + r*20 + 12);
            float sa = bb.x, sb = bb.y;
            sa=fmaf(a0.x,u0.x,sa); sb=fmaf(a0.x,u0.y,sb);
            sa=fmaf(a0.y,u1.x,sa); sb=fmaf(a0.y,u1.y,sb);
            sa=fmaf(a0.z,u2.x,sa); sb=fmaf(a0.z,u2.y,sb);
            sa=fmaf(a0.w,u3.x,sa); sb=fmaf(a0.w,u3.y,sb);
            sa=fmaf(a1.x,u4.x,sa); sb=fmaf(a1.x,u4.y,sb);
            sa=fmaf(a1.y,u5.x,sa); sb=fmaf(a1.y,u5.y,sb);
            sa=fmaf(a1.z,u6.x,sa); sb=fmaf(a1.z,u6.y,sb);
            sa=fmaf(a1.w,u7.x,sa); sb=fmaf(a1.w,u7.y,sb);
            sa=fmaf(a2.x,u8.x,sa); sb=fmaf(a2.x,u8.y,sb);
            sa=fmaf(a2.y,u9.x,sa); sb=fmaf(a2.y,u9.y,sb);
            sa=fmaf(a2.z,uA.x,sa); sb=fmaf(a2.z,uA.y,sb);
            sa=fmaf(a2.w,uB.x,sa); sb=fmaf(a2.w,uB.y,sb);
            sa=fmaf(a3.x,uC.x,sa); sb=fmaf(a3.x,uC.y,sb);
            sa=fmaf(a3.y,uD.x,sa); sb=fmaf(a3.y,uD.y,sb);
            sa=fmaf(a3.z,uE.x,sa); sb=fmaf(a3.z,uE.y,sb);
            sa=fmaf(a3.w,uF.x,sa); sb=fmaf(a3.w,uF.y,sb);
            dac[m][0] = fmaxf(sa, 0.f); dac[m][1] = fmaxf(sb, 0.f);
        }
        __syncthreads();          // all z reads done
        #pragma unroll
        for (int m = 0; m < 8; ++m)
            ST2(AR + (st + 32*m)*20 + ot*2) = make_float2(dac[m][0], dac[m][1]);
    }
    __syncthreads();

    // ================= xhat: K=16, N=128 (2 halves, prefetch h1) + rec =======
    float rp[8] = {0.f,0.f,0.f,0.f,0.f,0.f,0.f,0.f};
    float4 rw2 = GL4(Wd2[(size_t)wr*128 + 64 + wc]);   // prefetch half1
    {
        float accx[8][8];
        INIT88(accx, bd2, job);
        #pragma unroll
        for (int kc = 0; kc < 4; ++kc) K4(accx, AR, 20, kc, WB, 68, job, kc);
        #pragma unroll
        for (int m = 0; m < 8; ++m) {
            const int r = st + 32*m;
            const float4 xa = GL4(x[(size_t)(s0+r)*128 + job]);
            const float4 xb = GL4(x[(size_t)(s0+r)*128 + job + 4]);
            float df;
            df=accx[m][0]-xa.x; rp[m]=fmaf(df,df,rp[m]);
            df=accx[m][1]-xa.y; rp[m]=fmaf(df,df,rp[m]);
            df=accx[m][2]-xa.z; rp[m]=fmaf(df,df,rp[m]);
            df=accx[m][3]-xa.w; rp[m]=fmaf(df,df,rp[m]);
            df=accx[m][4]-xb.x; rp[m]=fmaf(df,df,rp[m]);
            df=accx[m][5]-xb.y; rp[m]=fmaf(df,df,rp[m]);
            df=accx[m][6]-xb.z; rp[m]=fmaf(df,df,rp[m]);
            df=accx[m][7]-xb.w; rp[m]=fmaf(df,df,rp[m]);
            float4* o = reinterpret_cast<float4*>(&xhat[(size_t)(s0+r)*128 + job]);
            o[0] = make_float4(accx[m][0],accx[m][1],accx[m][2],accx[m][3]);
            o[1] = make_float4(accx[m][4],accx[m][5],accx[m][6],accx[m][7]);
        }
    }
    __syncthreads();
    ST4(WB + wr*68 + wc) = rw2;
    __syncthreads();
    {
        float accx[8][8];
        INIT88(accx, bd2, 64 + job);
        #pragma unroll
        for (int kc = 0; kc < 4; ++kc) K4(accx, AR, 20, kc, WB, 68, job, kc);
        #pragma unroll
        for (int m = 0; m < 8; ++m) {
            const int r = st + 32*m;
            const float4 xa = GL4(x[(size_t)(s0+r)*128 + 64 + job]);
            const float4 xb = GL4(x[(size_t)(s0+r)*128 + 64 + job + 4]);
            float df;
            df=accx[m][0]-xa.x; rp[m]=fmaf(df,df,rp[m]);
            df=accx[m][1]-xa.y; rp[m]=fmaf(df,df,rp[m]);
            df=accx[m][2]-xa.z; rp[m]=fmaf(df,df,rp[m]);
            df=accx[m][3]-xa.w; rp[m]=fmaf(df,df,rp[m]);
            df=accx[m][4]-xb.x; rp[m]=fmaf(df,df,rp[m]);
            df=accx[m][5]-xb.y; rp[m]=fmaf(df,df,rp[m]);
            df=accx[m][6]-xb.z; rp[m]=fmaf(df,df,rp[m]);
            df=accx[m][7]-xb.w; rp[m]=fmaf(df,df,rp[m]);
            float4* o = reinterpret_cast<float4*>(&xhat[(size_t)(s0+r)*128 + 64 + job]);
            o[0] = make_float4(accx[m][0],accx[m][1],accx[m][2],accx[m][3]);
            o[1] = make_float4(accx[m][4],accx[m][5],accx[m][6],accx[m][7]);
        }
    }
    #pragma unroll
    for (int m = 0; m < 8; ++m) {
        float v = rp[m];
        v += __shfl_xor(v, 1); v += __shfl_xor(v, 2); v += __shfl_xor(v, 4);
        if (ot == 0) rec[s0 + st + 32*m] = v * (1.f/128.f);
    }
}

// ---------------------------------------------------------------------------
__global__ void k_scan(const int* __restrict__ counts,
                       int* __restrict__ bases, int* __restrict__ cursors)
{
    if (threadIdx.x == 0) {
        int acc = 0;
        for (int k = 0; k < KC; ++k) { bases[k] = acc; cursors[k] = acc; acc += counts[k]; }
    }
}

__global__ __launch_bounds__(256) void k_scatter(
    const int* __restrict__ cidx, int* __restrict__ cursors, int* __restrict__ seg)
{
    const int s = blockIdx.x * 256 + threadIdx.x;
    const int lane = threadIdx.x & 63;
    const int ci = cidx[s];
    #pragma unroll
    for (int k = 0; k < KC; ++k) {
        const u64 mk = __ballot(ci == k);
        if (ci == k) {
            const int leader = __ffsll(mk) - 1;
            int base = 0;
            if (lane == leader) base = atomicAdd(&cursors[k], (int)__popcll(mk));
            base = __shfl(base, leader, 64);
            seg[base + (int)__popcll(mk & (((u64)1 << lane) - 1))] = s;
        }
    }
}

// ---------------------------------------------------------------------------
// k_heads: same skeleton. AR [256][68] arena (staging [256][20] overlay),
// WB [16][68]. 18496 words = 73984 B + idxs -> 2 blocks/CU.
// ---------------------------------------------------------------------------
#define SMH 18496

__global__ __launch_bounds__(256, 1) void k_heads(
    const float* __restrict__ x, const float* __restrict__ zread,
    const float* __restrict__ Wh1, const float* __restrict__ bh1,
    const float* __restrict__ Wh2, const float* __restrict__ bh2,
    const int* __restrict__ counts, const int* __restrict__ bases,
    const int* __restrict__ seg,
    float* __restrict__ surv)
{
    __shared__ float sm[SMH];
    __shared__ int idxs[256];
    const int t  = threadIdx.x;
    const int ot = t & 7, st = t >> 3;
    const int job = ot * 8;
    const int xr0 = t >> 2, xc = (t & 3) * 4;
    const int wr  = t >> 4, wc = (t & 15) * 4;

    int kk = -1, chunk = 0, pref = 0;
    #pragma unroll
    for (int q = 0; q < KC; ++q) {
        const int ck = (counts[q] + 255) >> 8;
        if (kk < 0) {
            if ((int)blockIdx.x < pref + ck) { kk = q; chunk = (int)blockIdx.x - pref; }
            pref += ck;
        }
    }
    if (kk < 0) return;                     // block-uniform, before any barrier
    kk    = __builtin_amdgcn_readfirstlane(kk);
    chunk = __builtin_amdgcn_readfirstlane(chunk);
    const int cnt  = __builtin_amdgcn_readfirstlane(counts[kk]);
    const int base = __builtin_amdgcn_readfirstlane(bases[kk]);

    {   const int i = chunk*256 + t;
        idxs[t] = seg[base + ((i < cnt) ? i : (cnt - 1))]; }
    __syncthreads();
    const int i0 = idxs[xr0], i1 = idxs[xr0+64], i2 = idxs[xr0+128], i3 = idxs[xr0+192];

    // ================= head L1: K=144 (z chunk + 8 x chunks, T14) =============
    {
        float acc1[8][8];
        INIT88(acc1, bh1, (size_t)kk*64 + job);
        // stage gathered z (cols 0..15) + Wh1 z-rows
        {   const int zc = (t & 3) * 4;
            ST4(AR + (xr0      )*20 + zc) = GL4(zread[(size_t)i0*16 + zc]);
            ST4(AR + (xr0 +  64)*20 + zc) = GL4(zread[(size_t)i1*16 + zc]);
            ST4(AR + (xr0 + 128)*20 + zc) = GL4(zread[(size_t)i2*16 + zc]);
            ST4(AR + (xr0 + 192)*20 + zc) = GL4(zread[(size_t)i3*16 + zc]);
            ST4(WB + wr*68 + wc) = GL4(Wh1[((size_t)kk*144 + wr)*64 + wc]); }
        __syncthreads();
        // prefetch x chunk 0 + W chunk 0 (hidden under z-compute)
        float4 rx0 = GL4(x[(size_t)i0*128 + xc]);
        float4 rx1 = GL4(x[(size_t)i1*128 + xc]);
        float4 rx2 = GL4(x[(size_t)i2*128 + xc]);
        float4 rx3 = GL4(x[(size_t)i3*128 + xc]);
        float4 rw  = GL4(Wh1[((size_t)kk*144 + 16 + wr)*64 + wc]);
        #pragma unroll
        for (int kc = 0; kc < 4; ++kc) K4(acc1, AR, 20, kc, WB, 68, job, kc);
        #pragma unroll 1
        for (int c = 0; c < 8; ++c) {
            __syncthreads();                  // prev reads done
            STAGE_X();
            ST4(WB + wr*68 + wc) = rw;
            __syncthreads();
            if (c < 7) {
                rx0 = GL4(x[(size_t)i0*128 + (c+1)*16 + xc]);
                rx1 = GL4(x[(size_t)i1*128 + (c+1)*16 + xc]);
                rx2 = GL4(x[(size_t)i2*128 + (c+1)*16 + xc]);
                rx3 = GL4(x[(size_t)i3*128 + (c+1)*16 + xc]);
                rw  = GL4(Wh1[((size_t)kk*144 + 16 + (c+1)*16 + wr)*64 + wc]);
            }
            #pragma unroll
            for (int kc = 0; kc < 4; ++kc) K4(acc1, AR, 20, kc, WB, 68, job, kc);
        }
        __syncthreads();
        RELU88(acc1);
        WRITE_E(acc1);            // h1 -> arena stride 68
    }

    // ================= head L2: K=64 in 4 chunks (prefetched), N=64 padded ====
    float acc2[8][8];
    {   float bz[8];
        #pragma unroll
        for (int j = 0; j < 8; ++j) {
            const int col = job + j;
            bz[j] = (col < 50) ? bh2[(size_t)kk*50 + col] : 0.f;
        }
        #pragma unroll
        for (int m = 0; m < 8; ++m) {
            #pragma unroll
            for (int j = 0; j < 8; ++j) acc2[m][j] = bz[j];
        } }
    float4 rv;
    {   const int gk = wr;
        rv.x = (wc+0 < 50) ? Wh2[((size_t)kk*64 + gk)*50 + wc+0] : 0.f;
        rv.y = (wc+1 < 50) ? Wh2[((size_t)kk*64 + gk)*50 + wc+1] : 0.f;
        rv.z = (wc+2 < 50) ? Wh2[((size_t)kk*64 + gk)*50 + wc+2] : 0.f;
        rv.w = (wc+3 < 50) ? Wh2[((size_t)kk*64 + gk)*50 + wc+3] : 0.f; }
    #pragma unroll 1
    for (int c = 0; c < 4; ++c) {
        __syncthreads();                      // h1 visible / WB free
        ST4(WB + wr*68 + wc) = rv;
        __syncthreads();
        if (c < 3) {
            const int gk = (c+1)*16 + wr;
            rv.x = (wc+0 < 50) ? Wh2[((size_t)kk*64 + gk)*50 + wc+0] : 0.f;
            rv.y = (wc+1 < 50) ? Wh2[((size_t)kk*64 + gk)*50 + wc+1] : 0.f;
            rv.z = (wc+2 < 50) ? Wh2[((size_t)kk*64 + gk)*50 + wc+2] : 0.f;
            rv.w = (wc+3 < 50) ? Wh2[((size_t)kk*64 + gk)*50 + wc+3] : 0.f;
        }
        #pragma unroll
        for (int kc = 0; kc < 4; ++kc) K4(acc2, AR, 68, c*4 + kc, WB, 68, job, kc);
    }

    // ================= store surv (cols < 50, rows < cnt) =================
    #pragma unroll
    for (int m = 0; m < 8; ++m) {
        const int r = st + 32*m;
        if (chunk*256 + r < cnt) {
            float* so = &surv[(size_t)idxs[r]*50 + job];   // 8B-aligned (200B rows)
            if (ot < 6) {
                *reinterpret_cast<float2*>(&so[0]) = make_float2(acc2[m][0], acc2[m][1]);
                *reinterpret_cast<float2*>(&so[2]) = make_float2(acc2[m][2], acc2[m][3]);
                *reinterpret_cast<float2*>(&so[4]) = make_float2(acc2[m][4], acc2[m][5]);
                *reinterpret_cast<float2*>(&so[6]) = make_float2(acc2[m][6], acc2[m][7]);
            } else if (ot == 6) {
                *reinterpret_cast<float2*>(&so[0]) = make_float2(acc2[m][0], acc2[m][1]);
            }
        }
    }
}

// ---------------------------------------------------------------------------
extern "C" void kernel_launch(void* const* d_in, const int* in_sizes, int n_in,
                              void* d_out, int out_size, void* d_ws, size_t ws_size,
                              hipStream_t stream)
{
    const float* x   = (const float*)d_in[0];
    const float* We1 = (const float*)d_in[1];
    const float* be1 = (const float*)d_in[2];
    const float* We2 = (const float*)d_in[3];
    const float* be2 = (const float*)d_in[4];
    const float* We3 = (const float*)d_in[5];
    const float* be3 = (const float*)d_in[6];
    const float* Wd1 = (const float*)d_in[7];
    const float* bd1 = (const float*)d_in[8];
    const float* Wd2 = (const float*)d_in[9];
    const float* bd2 = (const float*)d_in[10];
    const float* Wh1 = (const float*)d_in[11];
    const float* bh1 = (const float*)d_in[12];
    const float* Wh2 = (const float*)d_in[13];
    const float* bh2 = (const float*)d_in[14];
    const float* cen = (const float*)d_in[15];
    float* out = (float*)d_out;

    float* out_z  = out;
    float* out_q  = out + (size_t)NS * 16;
    float* out_sv = out + (size_t)NS * 24;
    float* out_xh = out + (size_t)NS * 74;
    float* out_rc = out + (size_t)NS * 202;
    float* out_kl = out + (size_t)NS * 203;

    int* cidx    = (int*)d_ws;       // [NS]
    int* counts  = cidx + NS;        // [8]
    int* bases   = counts + KC;      // [8]
    int* cursors = bases + KC;       // [8]
    int* seg     = cursors + KC;     // [NS]

    hipMemsetAsync(counts, 0, KC * sizeof(int), stream);

    k_enc<<<dim3(NS / 256), dim3(256), 0, stream>>>(
        x, We1, be1, We2, be2, We3, be3, Wd1, bd1, Wd2, bd2, cen,
        out_z, out_q, out_xh, out_rc, out_kl, cidx, counts);

    k_scan<<<dim3(1), dim3(64), 0, stream>>>(counts, bases, cursors);

    k_scatter<<<dim3(NS / 256), dim3(256), 0, stream>>>(cidx, cursors, seg);

    k_heads<<<dim3(NS / 256 + KC), dim3(256), 0, stream>>>(
        x, out_z, Wh1, bh1, Wh2, bh2, counts, bases, seg, out_sv);
}

// Round 10
// 446.993 us; speedup vs baseline: 1.1221x; 1.1221x over previous
//
#include <hip/hip_runtime.h>

#define NS 131072
#define KC 8
typedef unsigned long long u64;

#define LD4(P) (*reinterpret_cast<const float4*>(&sm[(P)]))
#define ST4(P) (*reinterpret_cast<float4*>(&sm[(P)]))
#define GL4(P) (*reinterpret_cast<const float4*>(&(P)))

#define FMA4(ACCR, AV, B) do { \
  ACCR[0]=fmaf((AV),(B).x,ACCR[0]); ACCR[1]=fmaf((AV),(B).y,ACCR[1]); \
  ACCR[2]=fmaf((AV),(B).z,ACCR[2]); ACCR[3]=fmaf((AV),(B).w,ACCR[3]); } while(0)

// 4-wide K step, 8 samples x 4 outputs: 12 LDS b128 reads / 128 FMAs.
// B-reads: 16 distinct addrs (full 64-col row) -> 2-way = free.
// A-reads: 4 distinct addrs (st 0..3 in wave) -> 16-lane broadcast = free.
#define K4(ACC, ABASE, ASTR, AK, BBASE, BSTR, JOFF, BK) do { \
  const float4 b0=LD4((BBASE)+((BK)*4+0)*(BSTR)+(JOFF)); \
  const float4 b1=LD4((BBASE)+((BK)*4+1)*(BSTR)+(JOFF)); \
  const float4 b2=LD4((BBASE)+((BK)*4+2)*(BSTR)+(JOFF)); \
  const float4 b3=LD4((BBASE)+((BK)*4+3)*(BSTR)+(JOFF)); \
  _Pragma("unroll") \
  for (int m_ = 0; m_ < 8; ++m_) { \
    const float4 av = LD4((ABASE)+(st+16*m_)*(ASTR)+(AK)*4); \
    FMA4(ACC[m_], av.x, b0); FMA4(ACC[m_], av.y, b1); \
    FMA4(ACC[m_], av.z, b2); FMA4(ACC[m_], av.w, b3); } \
} while(0)

#define INIT84(ACC, BPTR, OFF) do { \
  const float4 u_ = *reinterpret_cast<const float4*>(&(BPTR)[(OFF)]); \
  _Pragma("unroll") for (int m_=0;m_<8;++m_){ \
    ACC[m_][0]=u_.x; ACC[m_][1]=u_.y; ACC[m_][2]=u_.z; ACC[m_][3]=u_.w; } } while(0)

#define RELU84(ACC) do { _Pragma("unroll") for (int m_=0;m_<8;++m_) \
  { _Pragma("unroll") for (int j_=0;j_<4;++j_) ACC[m_][j_]=fmaxf(ACC[m_][j_],0.f); } } while(0)

// write 8x4 reg tile into arena rows (stride 68), cols job..job+3
#define WRITE_E(ACC) do { _Pragma("unroll") for (int m_=0;m_<8;++m_){ \
  ST4(AR + (st+16*m_)*68 + job) = \
    make_float4(ACC[m_][0],ACC[m_][1],ACC[m_][2],ACC[m_][3]); } } while(0)

// staged-register -> LDS [128][20] staging layout
#define STAGE_X() do { \
  ST4(AR + xr0*20 + xcc)     = rx0; \
  ST4(AR + xr0*20 + xcc + 4) = rx1; } while(0)

// ---------------------------------------------------------------------------
// Block = 128 samples x 256 threads; thread = (st = t>>4: 8 rows st+16m,
// ot = t&15: 4 cols job=ot*4). 32 accums -> VGPR ~100 (cap 128 via
// __launch_bounds__(256,2)) -> 16 waves/CU; LDS 39.2KB -> 4 blocks/CU.
// Arena (words): AR [0,8704) = staging [128][20] -> e1/e2 [128][68] ->
// z/d [128][20] (+Wd1 [16][16] at AR+2560, free while z/d live);
// WB [8704,9792) = weight chunks [16][68]. 9792 w = 39168 B.
// ---------------------------------------------------------------------------
#define AR   0
#define WD1i 2560
#define WB   8704
#define SMW  9792

__global__ __launch_bounds__(256, 2) void k_enc(
    const float* __restrict__ x,
    const float* __restrict__ We1, const float* __restrict__ be1,
    const float* __restrict__ We2, const float* __restrict__ be2,
    const float* __restrict__ We3, const float* __restrict__ be3,
    const float* __restrict__ Wd1, const float* __restrict__ bd1,
    const float* __restrict__ Wd2, const float* __restrict__ bd2,
    const float* __restrict__ centers,
    float* __restrict__ out_z, float* __restrict__ out_q,
    float* __restrict__ xhat, float* __restrict__ rec, float* __restrict__ kld,
    int* __restrict__ cidx, int* __restrict__ counts)
{
    __shared__ float sm[SMW];
    const int t  = threadIdx.x;
    const int ot = t & 15, st = t >> 4;
    const int job = ot * 4;
    const int s0 = blockIdx.x * 128;
    const int xr0 = t >> 1, xcc = (t & 1) * 8;     // x-staging mapping
    const int wr  = t >> 4, wc  = (t & 15) * 4;    // weight-staging mapping

    // ================= L1: K=128, 8 chunks of 16, T14 prefetch ==============
    {
        float acc1[8][4];
        INIT84(acc1, be1, job);
        float4 rx0 = GL4(x[(size_t)(s0+xr0)*128 + xcc]);
        float4 rx1 = GL4(x[(size_t)(s0+xr0)*128 + xcc + 4]);
        float4 rw  = GL4(We1[(size_t)wr*64 + wc]);
        #pragma unroll 1
        for (int c = 0; c < 8; ++c) {
            __syncthreads();                      // prev chunk reads done
            STAGE_X();
            ST4(WB + wr*68 + wc) = rw;
            __syncthreads();                      // staging visible
            if (c < 7) {
                rx0 = GL4(x[(size_t)(s0+xr0)*128 + (c+1)*16 + xcc]);
                rx1 = GL4(x[(size_t)(s0+xr0)*128 + (c+1)*16 + xcc + 4]);
                rw  = GL4(We1[(size_t)((c+1)*16 + wr)*64 + wc]);
            }
            #pragma unroll
            for (int kc = 0; kc < 4; ++kc) K4(acc1, AR, 20, kc, WB, 68, job, kc);
        }
        __syncthreads();
        RELU84(acc1);
        WRITE_E(acc1);                            // e1 -> arena stride 68
    }

    // ================= L2: K=64, 4 weight chunks, T14 prefetch ==============
    {
        float acc2[8][4];
        INIT84(acc2, be2, job);
        float4 rw = GL4(We2[(size_t)wr*64 + wc]);
        #pragma unroll 1
        for (int c = 0; c < 4; ++c) {
            __syncthreads();                      // e1 visible / prev K4 done
            ST4(WB + wr*68 + wc) = rw;
            __syncthreads();
            if (c < 3) rw = GL4(We2[(size_t)((c+1)*16 + wr)*64 + wc]);
            #pragma unroll
            for (int kc = 0; kc < 4; ++kc) K4(acc2, AR, 68, c*4 + kc, WB, 68, job, kc);
        }
        __syncthreads();
        RELU84(acc2);
        WRITE_E(acc2);                            // e2 overwrites e1
    }
    // stage W3 [64][16] -> WB
    {   const int row = t >> 2, c4 = (t & 3) * 4;
        ST4(WB + row*16 + c4) = GL4(We3[(size_t)row*16 + c4]); }
    __syncthreads();

    // ================= L3: z, K=64, 1 col/thread (col = ot) =================
    float zac[8];
    {   const float b3v = be3[ot];
        #pragma unroll
        for (int m = 0; m < 8; ++m) zac[m] = b3v; }
    #pragma unroll 2
    for (int kc = 0; kc < 16; ++kc) {
        const float w0 = sm[WB + (kc*4+0)*16 + ot];
        const float w1 = sm[WB + (kc*4+1)*16 + ot];
        const float w2 = sm[WB + (kc*4+2)*16 + ot];
        const float w3 = sm[WB + (kc*4+3)*16 + ot];
        #pragma unroll
        for (int m = 0; m < 8; ++m) {
            const float4 av = LD4(AR + (st + 16*m)*68 + kc*4);
            float s = zac[m];
            s = fmaf(av.x, w0, s); s = fmaf(av.y, w1, s);
            s = fmaf(av.z, w2, s); s = fmaf(av.w, w3, s);
            zac[m] = s;
        }
    }
    #pragma unroll
    for (int m = 0; m < 8; ++m)
        out_z[(size_t)(s0 + st + 16*m)*16 + ot] = zac[m];
    __syncthreads();              // all e2 + W3 reads done
    #pragma unroll
    for (int m = 0; m < 8; ++m) sm[AR + (st + 16*m)*20 + ot] = zac[m];
    ST4(WB + wr*68 + wc) = GL4(Wd2[(size_t)wr*128 + wc]);      // Wd2 half0
    if (t < 64) ST4(WD1i + (t >> 2)*16 + (t & 3)*4) =
        GL4(Wd1[(t >> 2)*16 + (t & 3)*4]);
    __syncthreads();

    // ======== rows t<128 (waves 0,1): student-t + softmax + argmax ==========
    if (t < 128) {
        const float4 z0 = LD4(AR + t*20 + 0), z1 = LD4(AR + t*20 + 4);
        const float4 z2 = LD4(AR + t*20 + 8), z3 = LD4(AR + t*20 + 12);
        const float zz[16] = {z0.x,z0.y,z0.z,z0.w, z1.x,z1.y,z1.z,z1.w,
                              z2.x,z2.y,z2.z,z2.w, z3.x,z3.y,z3.z,z3.w};
        float d2[KC];
        #pragma unroll
        for (int k = 0; k < KC; ++k) {
            float acc = 0.f;
            #pragma unroll
            for (int l = 0; l < 16; ++l) {
                const float dl = zz[l] - centers[k*16 + l];
                acc = fmaf(dl, dl, acc);
            }
            d2[k] = acc;
        }
        float lgt[KC], ex[KC];
        float mm = -1e30f;
        #pragma unroll
        for (int k = 0; k < KC; ++k) { lgt[k] = -log1pf(d2[k]); mm = fmaxf(mm, lgt[k]); }
        float ssum = 0.f;
        #pragma unroll
        for (int k = 0; k < KC; ++k) { ex[k] = expf(lgt[k] - mm); ssum += ex[k]; }
        const float inv = 1.f / ssum;
        float4* oq = reinterpret_cast<float4*>(&out_q[(size_t)(s0 + t)*8]);
        oq[0] = make_float4(ex[0]*inv, ex[1]*inv, ex[2]*inv, ex[3]*inv);
        oq[1] = make_float4(ex[4]*inv, ex[5]*inv, ex[6]*inv, ex[7]*inv);
        int ci = 0; float best = d2[0];
        #pragma unroll
        for (int k = 1; k < KC; ++k) if (d2[k] < best) { best = d2[k]; ci = k; }
        cidx[s0 + t] = ci;
        #pragma unroll
        for (int k = 0; k < KC; ++k) {
            const u64 mk = __ballot(ci == k);
            if ((t & 63) == 0 && mk) atomicAdd(&counts[k], (int)__popcll(mk));
        }
        kld[s0 + t] = 0.f;
    }

    // ================= decoder: d = relu(z Wd1 + bd1), col = ot =============
    {
        float w[16];
        #pragma unroll
        for (int k = 0; k < 16; ++k) w[k] = sm[WD1i + k*16 + ot];
        const float bb = bd1[ot];
        float dac[8];
        #pragma unroll
        for (int m = 0; m < 8; ++m) {
            const int r = st + 16*m;
            float s = bb;
            #pragma unroll
            for (int kc = 0; kc < 4; ++kc) {
                const float4 av = LD4(AR + r*20 + kc*4);
                s = fmaf(av.x, w[kc*4+0], s); s = fmaf(av.y, w[kc*4+1], s);
                s = fmaf(av.z, w[kc*4+2], s); s = fmaf(av.w, w[kc*4+3], s);
            }
            dac[m] = fmaxf(s, 0.f);
        }
        __syncthreads();          // all z reads done
        #pragma unroll
        for (int m = 0; m < 8; ++m) sm[AR + (st + 16*m)*20 + ot] = dac[m];
    }
    __syncthreads();

    // ================= xhat: K=16, N=128 (2 halves of 64) + rec =============
    float rp[8] = {0.f,0.f,0.f,0.f,0.f,0.f,0.f,0.f};
    float4 rw2 = GL4(Wd2[(size_t)wr*128 + 64 + wc]);   // prefetch half1
    {
        float accx[8][4];
        INIT84(accx, bd2, job);
        #pragma unroll
        for (int kc = 0; kc < 4; ++kc) K4(accx, AR, 20, kc, WB, 68, job, kc);
        #pragma unroll
        for (int m = 0; m < 8; ++m) {
            const int r = st + 16*m;
            const float4 xa = GL4(x[(size_t)(s0+r)*128 + job]);
            float df;
            df=accx[m][0]-xa.x; rp[m]=fmaf(df,df,rp[m]);
            df=accx[m][1]-xa.y; rp[m]=fmaf(df,df,rp[m]);
            df=accx[m][2]-xa.z; rp[m]=fmaf(df,df,rp[m]);
            df=accx[m][3]-xa.w; rp[m]=fmaf(df,df,rp[m]);
            *reinterpret_cast<float4*>(&xhat[(size_t)(s0+r)*128 + job]) =
                make_float4(accx[m][0],accx[m][1],accx[m][2],accx[m][3]);
        }
    }
    __syncthreads();
    ST4(WB + wr*68 + wc) = rw2;
    __syncthreads();
    {
        float accx[8][4];
        INIT84(accx, bd2, 64 + job);
        #pragma unroll
        for (int kc = 0; kc < 4; ++kc) K4(accx, AR, 20, kc, WB, 68, job, kc);
        #pragma unroll
        for (int m = 0; m < 8; ++m) {
            const int r = st + 16*m;
            const float4 xa = GL4(x[(size_t)(s0+r)*128 + 64 + job]);
            float df;
            df=accx[m][0]-xa.x; rp[m]=fmaf(df,df,rp[m]);
            df=accx[m][1]-xa.y; rp[m]=fmaf(df,df,rp[m]);
            df=accx[m][2]-xa.z; rp[m]=fmaf(df,df,rp[m]);
            df=accx[m][3]-xa.w; rp[m]=fmaf(df,df,rp[m]);
            *reinterpret_cast<float4*>(&xhat[(size_t)(s0+r)*128 + 64 + job]) =
                make_float4(accx[m][0],accx[m][1],accx[m][2],accx[m][3]);
        }
    }
    #pragma unroll
    for (int m = 0; m < 8; ++m) {
        float v = rp[m];
        v += __shfl_xor(v, 1); v += __shfl_xor(v, 2);
        v += __shfl_xor(v, 4); v += __shfl_xor(v, 8);
        if (ot == 0) rec[s0 + st + 16*m] = v * (1.f/128.f);
    }
}

// ---------------------------------------------------------------------------
__global__ void k_scan(const int* __restrict__ counts,
                       int* __restrict__ bases, int* __restrict__ cursors)
{
    if (threadIdx.x == 0) {
        int acc = 0;
        for (int k = 0; k < KC; ++k) { bases[k] = acc; cursors[k] = acc; acc += counts[k]; }
    }
}

__global__ __launch_bounds__(256) void k_scatter(
    const int* __restrict__ cidx, int* __restrict__ cursors, int* __restrict__ seg)
{
    const int s = blockIdx.x * 256 + threadIdx.x;
    const int lane = threadIdx.x & 63;
    const int ci = cidx[s];
    #pragma unroll
    for (int k = 0; k < KC; ++k) {
        const u64 mk = __ballot(ci == k);
        if (ci == k) {
            const int leader = __ffsll(mk) - 1;
            int base = 0;
            if (lane == leader) base = atomicAdd(&cursors[k], (int)__popcll(mk));
            base = __shfl(base, leader, 64);
            seg[base + (int)__popcll(mk & (((u64)1 << lane) - 1))] = s;
        }
    }
}

// ---------------------------------------------------------------------------
// k_heads: same retiling. Block = 128 gathered samples; cluster kk uniform.
// ---------------------------------------------------------------------------
__global__ __launch_bounds__(256, 2) void k_heads(
    const float* __restrict__ x, const float* __restrict__ zread,
    const float* __restrict__ Wh1, const float* __restrict__ bh1,
    const float* __restrict__ Wh2, const float* __restrict__ bh2,
    const int* __restrict__ counts, const int* __restrict__ bases,
    const int* __restrict__ seg,
    float* __restrict__ surv)
{
    __shared__ float sm[SMW];
    __shared__ int idxs[128];
    const int t  = threadIdx.x;
    const int ot = t & 15, st = t >> 4;
    const int job = ot * 4;
    const int xr0 = t >> 1, xcc = (t & 1) * 8;
    const int wr  = t >> 4, wc  = (t & 15) * 4;

    int kk = -1, chunk = 0, pref = 0;
    #pragma unroll
    for (int q = 0; q < KC; ++q) {
        const int ck = (counts[q] + 127) >> 7;
        if (kk < 0) {
            if ((int)blockIdx.x < pref + ck) { kk = q; chunk = (int)blockIdx.x - pref; }
            pref += ck;
        }
    }
    if (kk < 0) return;                     // block-uniform, before any barrier
    kk    = __builtin_amdgcn_readfirstlane(kk);
    chunk = __builtin_amdgcn_readfirstlane(chunk);
    const int cnt  = __builtin_amdgcn_readfirstlane(counts[kk]);
    const int base = __builtin_amdgcn_readfirstlane(bases[kk]);

    if (t < 128) {
        const int i = chunk*128 + t;
        idxs[t] = seg[base + ((i < cnt) ? i : (cnt - 1))];
    }
    __syncthreads();
    const int irow = idxs[xr0];

    // ================= head L1: K=144 (z chunk + 8 x chunks, T14) ===========
    {
        float acc1[8][4];
        INIT84(acc1, bh1, (size_t)kk*64 + job);
        {   // stage gathered z [128][16] -> AR [128][20]; Wh1 z-rows -> WB
            ST4(AR + xr0*20 + xcc)     = GL4(zread[(size_t)irow*16 + xcc]);
            ST4(AR + xr0*20 + xcc + 4) = GL4(zread[(size_t)irow*16 + xcc + 4]);
            ST4(WB + wr*68 + wc) = GL4(Wh1[((size_t)kk*144 + wr)*64 + wc]); }
        __syncthreads();
        float4 rx0 = GL4(x[(size_t)irow*128 + xcc]);
        float4 rx1 = GL4(x[(size_t)irow*128 + xcc + 4]);
        float4 rw  = GL4(Wh1[((size_t)kk*144 + 16 + wr)*64 + wc]);
        #pragma unroll
        for (int kc = 0; kc < 4; ++kc) K4(acc1, AR, 20, kc, WB, 68, job, kc);
        #pragma unroll 1
        for (int c = 0; c < 8; ++c) {
            __syncthreads();
            STAGE_X();
            ST4(WB + wr*68 + wc) = rw;
            __syncthreads();
            if (c < 7) {
                rx0 = GL4(x[(size_t)irow*128 + (c+1)*16 + xcc]);
                rx1 = GL4(x[(size_t)irow*128 + (c+1)*16 + xcc + 4]);
                rw  = GL4(Wh1[((size_t)kk*144 + 16 + (c+1)*16 + wr)*64 + wc]);
            }
            #pragma unroll
            for (int kc = 0; kc < 4; ++kc) K4(acc1, AR, 20, kc, WB, 68, job, kc);
        }
        __syncthreads();
        RELU84(acc1);
        WRITE_E(acc1);            // h1 -> arena stride 68
    }

    // ================= head L2: K=64 in 4 chunks, cols job..job+3 ===========
    float acc2[8][4];
    {   float4 bz;
        bz.x = (job+0 < 50) ? bh2[(size_t)kk*50 + job+0] : 0.f;
        bz.y = (job+1 < 50) ? bh2[(size_t)kk*50 + job+1] : 0.f;
        bz.z = (job+2 < 50) ? bh2[(size_t)kk*50 + job+2] : 0.f;
        bz.w = (job+3 < 50) ? bh2[(size_t)kk*50 + job+3] : 0.f;
        #pragma unroll
        for (int m = 0; m < 8; ++m) {
            acc2[m][0] = bz.x; acc2[m][1] = bz.y;
            acc2[m][2] = bz.z; acc2[m][3] = bz.w;
        } }
    float4 rv;
    {   const int gk = wr;
        rv.x = (wc+0 < 50) ? Wh2[((size_t)kk*64 + gk)*50 + wc+0] : 0.f;
        rv.y = (wc+1 < 50) ? Wh2[((size_t)kk*64 + gk)*50 + wc+1] : 0.f;
        rv.z = (wc+2 < 50) ? Wh2[((size_t)kk*64 + gk)*50 + wc+2] : 0.f;
        rv.w = (wc+3 < 50) ? Wh2[((size_t)kk*64 + gk)*50 + wc+3] : 0.f; }
    #pragma unroll 1
    for (int c = 0; c < 4; ++c) {
        __syncthreads();                      // h1 visible / WB free
        ST4(WB + wr*68 + wc) = rv;
        __syncthreads();
        if (c < 3) {
            const int gk = (c+1)*16 + wr;
            rv.x = (wc+0 < 50) ? Wh2[((size_t)kk*64 + gk)*50 + wc+0] : 0.f;
            rv.y = (wc+1 < 50) ? Wh2[((size_t)kk*64 + gk)*50 + wc+1] : 0.f;
            rv.z = (wc+2 < 50) ? Wh2[((size_t)kk*64 + gk)*50 + wc+2] : 0.f;
            rv.w = (wc+3 < 50) ? Wh2[((size_t)kk*64 + gk)*50 + wc+3] : 0.f;
        }
        #pragma unroll
        for (int kc = 0; kc < 4; ++kc) K4(acc2, AR, 68, c*4 + kc, WB, 68, job, kc);
    }

    // ================= store surv (cols < 50, rows < cnt) ===================
    #pragma unroll
    for (int m = 0; m < 8; ++m) {
        const int r = st + 16*m;
        if (chunk*128 + r < cnt) {
            float* so = &surv[(size_t)idxs[r]*50 + job];   // 8B-aligned
            if (ot < 12) {
                *reinterpret_cast<float2*>(&so[0]) = make_float2(acc2[m][0], acc2[m][1]);
                *reinterpret_cast<float2*>(&so[2]) = make_float2(acc2[m][2], acc2[m][3]);
            } else if (ot == 12) {
                *reinterpret_cast<float2*>(&so[0]) = make_float2(acc2[m][0], acc2[m][1]);
            }
        }
    }
}

// ---------------------------------------------------------------------------
extern "C" void kernel_launch(void* const* d_in, const int* in_sizes, int n_in,
                              void* d_out, int out_size, void* d_ws, size_t ws_size,
                              hipStream_t stream)
{
    const float* x   = (const float*)d_in[0];
    const float* We1 = (const float*)d_in[1];
    const float* be1 = (const float*)d_in[2];
    const float* We2 = (const float*)d_in[3];
    const float* be2 = (const float*)d_in[4];
    const float* We3 = (const float*)d_in[5];
    const float* be3 = (const float*)d_in[6];
    const float* Wd1 = (const float*)d_in[7];
    const float* bd1 = (const float*)d_in[8];
    const float* Wd2 = (const float*)d_in[9];
    const float* bd2 = (const float*)d_in[10];
    const float* Wh1 = (const float*)d_in[11];
    const float* bh1 = (const float*)d_in[12];
    const float* Wh2 = (const float*)d_in[13];
    const float* bh2 = (const float*)d_in[14];
    const float* cen = (const float*)d_in[15];
    float* out = (float*)d_out;

    float* out_z  = out;
    float* out_q  = out + (size_t)NS * 16;
    float* out_sv = out + (size_t)NS * 24;
    float* out_xh = out + (size_t)NS * 74;
    float* out_rc = out + (size_t)NS * 202;
    float* out_kl = out + (size_t)NS * 203;

    int* cidx    = (int*)d_ws;       // [NS]
    int* counts  = cidx + NS;        // [8]
    int* bases   = counts + KC;      // [8]
    int* cursors = bases + KC;       // [8]
    int* seg     = cursors + KC;     // [NS]

    hipMemsetAsync(counts, 0, KC * sizeof(int), stream);

    k_enc<<<dim3(NS / 128), dim3(256), 0, stream>>>(
        x, We1, be1, We2, be2, We3, be3, Wd1, bd1, Wd2, bd2, cen,
        out_z, out_q, out_xh, out_rc, out_kl, cidx, counts);

    k_scan<<<dim3(1), dim3(64), 0, stream>>>(counts, bases, cursors);

    k_scatter<<<dim3(NS / 256), dim3(256), 0, stream>>>(cidx, cursors, seg);

    k_heads<<<dim3(NS / 128 + KC), dim3(256), 0, stream>>>(
        x, out_z, Wh1, bh1, Wh2, bh2, counts, bases, seg, out_sv);
}